// Round 2
// baseline (103.389 us; speedup 1.0000x reference)
//
#include <hip/hip_runtime.h>
#include <hip/hip_bf16.h>
#include <math.h>

// Problem constants
#define N_TOK 4096
#define W 512
#define F_TOT 1024
#define FW (F_TOT * W)   // 524288

// Workspace layout (bytes) — ~10.5 MB total
#define OFF_PARTIAL 0          // 256 floats: per-block max|freq| partials
#define OFF_NNZ     1024       // 1 uint: nonzero thr_w count
#define OFF_XN      4096       // 4096*512 bf16 = 4 MB (x_n, MFMA A operand)
#define OFF_WB      4198400    // 512*512 bf16 = 512 KB (w_loc, MFMA B operand)
#define OFF_E       4722688    // FW uints  (2 MB) nonzero thr_w element ids
#define OFF_T       6819840    // FW floats (2 MB) thr_w values
#define OFF_C       8916992    // FW floats (2 MB) scaled freqs

typedef __attribute__((ext_vector_type(8))) short bf16x8;
typedef __attribute__((ext_vector_type(4))) float f32x4;

// Kernel 1 (4096 blocks x 256):
//  - every block: LayerNorm one row of x (fp32 in) -> xn (bf16 in ws)
//  - blocks 0..255:   per-slice max|freq| partials (freq is fp32)
//  - blocks 512..1535: convert w_loc fp32 -> bf16 (wb in ws)
//  - block 0: zero the nnz counter (ws is 0xAA-poisoned each launch)
__global__ __launch_bounds__(256) void ln_prep(
    const float* __restrict__ x, const float* __restrict__ freq,
    const float* __restrict__ gamma, const float* __restrict__ beta,
    const float* __restrict__ wloc, __hip_bfloat16* __restrict__ xn,
    __hip_bfloat16* __restrict__ wb, float* __restrict__ partial,
    unsigned* __restrict__ nnz) {
  __shared__ float red[256];
  __shared__ float red2[256];
  const int n = blockIdx.x, t = threadIdx.x;
  const float v0 = x[n * W + t];
  const float v1 = x[n * W + t + 256];
  red[t] = v0 + v1;
  red2[t] = v0 * v0 + v1 * v1;
  __syncthreads();
  for (int s = 128; s > 0; s >>= 1) {
    if (t < s) { red[t] += red[t + s]; red2[t] += red2[t + s]; }
    __syncthreads();
  }
  const float mu = red[0] * (1.0f / W);
  const float var = red2[0] * (1.0f / W) - mu * mu;
  const float rstd = rsqrtf(var + 1e-5f);
  xn[n * W + t]       = __float2bfloat16((v0 - mu) * rstd * gamma[t] + beta[t]);
  xn[n * W + t + 256] = __float2bfloat16((v1 - mu) * rstd * gamma[t + 256] + beta[t + 256]);

  if (n < 256) {
    // slice of 2048 freq elements -> one partial max
    float m = 0.0f;
    const float* fp = freq + n * 2048;
#pragma unroll
    for (int j = 0; j < 8; ++j) m = fmaxf(m, fabsf(fp[t + j * 256]));
    __syncthreads();  // everyone done with red[0]/red2[0] before reuse
    red[t] = m;
    __syncthreads();
    for (int s = 128; s > 0; s >>= 1) {
      if (t < s) red[t] = fmaxf(red[t], red[t + s]);
      __syncthreads();
    }
    if (t == 0) {
      partial[n] = red[0];
      if (n == 0) *nnz = 0u;
    }
  } else if (n >= 512 && n < 1536) {
    const int i = (n - 512) * 256 + t;  // covers all 512*512 elements
    wb[i] = __float2bfloat16(wloc[i]);
  }
}

// Kernel 2: thr_w = sign(raw)*relu(|raw|-TAU)*win, compacted to nonzero list.
// win = exp(-6*(f/max|f|)^2), f = 0.8*freq (the 0.8 cancels in f/max|f| but
// cArr must hold f itself for sin(x*f)).
__global__ __launch_bounds__(256) void thr_compact(
    const float* __restrict__ freq, const float* __restrict__ alpha,
    const float* __restrict__ gate, const float* __restrict__ partial,
    unsigned* __restrict__ nnz, unsigned* __restrict__ eArr,
    float* __restrict__ tArr, float* __restrict__ cArr) {
  __shared__ float red[256];
  const int t = threadIdx.x;
  red[t] = partial[t];
  __syncthreads();
  for (int s = 128; s > 0; s >>= 1) {
    if (t < s) red[t] = fmaxf(red[t], red[t + s]);
    __syncthreads();
  }
  const float denom = red[0] * 0.8f;  // max|f|
  const bool tiny = denom < 1e-8f;
  const float inv = tiny ? 0.0f : (1.0f / denom);
  const int base = blockIdx.x * 1024 + t;
#pragma unroll
  for (int j = 0; j < 4; ++j) {
    const int e = base + j * 256;
    const float f = freq[e] * 0.8f;
    const float raw = alpha[e] * gate[e];
    const float v = fabsf(raw) - 1e-3f;  // TAU
    if (v > 0.0f) {
      const float r = f * inv;
      const float win = tiny ? 1.0f : expf(-6.0f * r * r);
      const float tw = copysignf(v, raw) * win;
      const unsigned idx = atomicAdd(nnz, 1u);
      eArr[idx] = (unsigned)e;
      tArr[idx] = tw;
      cArr[idx] = f;
    }
  }
}

// Kernel 3: h_local = GELU(xn @ wloc^T + b) via MFMA 16x16x32 bf16.
// One wave per 64x64 output tile, direct-from-global fragments (no LDS).
// A-frag: A[m=lane&15][k=(lane>>4)*8+j]  (8 contiguous bf16 = 16 B/lane)
// B-frag: B[k][n=lane&15], k=(lane>>4)*8+j  (wloc stored [N][K] = B^T)
// C/D:    col=lane&15, row=(lane>>4)*4+reg  [measured m89/m91]
__global__ __launch_bounds__(64) void gemm_gelu(
    const __hip_bfloat16* __restrict__ xn, const __hip_bfloat16* __restrict__ wb,
    const float* __restrict__ bias, float* __restrict__ out) {
  const int tm = blockIdx.x >> 3;   // 64 row tiles
  const int tn = blockIdx.x & 7;    // 8 col tiles
  const int lane = threadIdx.x;
  const int m = lane & 15;
  const int q = lane >> 4;
  const short* A = (const short*)xn + (tm * 64) * W;
  const short* B = (const short*)wb + (tn * 64) * W;
  f32x4 acc[4][4] = {};

  for (int k0 = 0; k0 < W; k0 += 32) {
    const int koff = k0 + q * 8;
    bf16x8 a[4], b[4];
#pragma unroll
    for (int i = 0; i < 4; ++i)
      a[i] = *(const bf16x8*)(A + (i * 16 + m) * W + koff);
#pragma unroll
    for (int j = 0; j < 4; ++j)
      b[j] = *(const bf16x8*)(B + (j * 16 + m) * W + koff);
#pragma unroll
    for (int i = 0; i < 4; ++i)
#pragma unroll
      for (int j = 0; j < 4; ++j)
        acc[i][j] = __builtin_amdgcn_mfma_f32_16x16x32_bf16(a[i], b[j], acc[i][j], 0, 0, 0);
  }

#pragma unroll
  for (int i = 0; i < 4; ++i) {
#pragma unroll
    for (int j = 0; j < 4; ++j) {
      const int col = tn * 64 + j * 16 + m;
      const float bv = bias[col];
#pragma unroll
      for (int r = 0; r < 4; ++r) {
        const int row = tm * 64 + i * 16 + q * 4 + r;
        const float v = acc[i][j][r] + bv;
        const float g = 0.5f * v * (1.0f + erff(v * 0.70710678118654752f));
        out[row * W + col] = g;
      }
    }
  }
}

// Kernel 4: spectral accumulation + RMS norm + residual add (gather-style).
// For the actual inputs nnz==0 -> immediate exit (out already = h_local).
__global__ __launch_bounds__(256) void spectral_final(
    const __hip_bfloat16* __restrict__ xn, const unsigned* __restrict__ nnz,
    const unsigned* __restrict__ eArr, const float* __restrict__ tArr,
    const float* __restrict__ cArr, float* __restrict__ out) {
  const unsigned cnt = *nnz;
  if (cnt == 0) return;
  __shared__ float red[256];
  const int t = threadIdx.x;
  for (int n = blockIdx.x; n < N_TOK; n += gridDim.x) {
    const int c0 = t, c1 = t + 256;
    const float x0 = __bfloat162float(xn[n * W + c0]);
    const float x1 = __bfloat162float(xn[n * W + c1]);
    float h0 = 0.0f, h1 = 0.0f;
    for (unsigned i = 0; i < cnt; ++i) {
      const unsigned e = eArr[i];
      const int we = (int)(e & (W - 1));
      const float tw = tArr[i];
      const float cf = cArr[i];
      if (we == c0) h0 += tw * sinf(x0 * cf);
      else if (we == c1) h1 += tw * sinf(x1 * cf);
    }
    red[t] = h0 * h0 + h1 * h1;
    __syncthreads();
    for (int s = 128; s > 0; s >>= 1) {
      if (t < s) red[t] += red[t + s];
      __syncthreads();
    }
    const float rms = sqrtf(red[0] * (1.0f / W) + 1e-8f);
    const float sc = 0.25f / rms;
    out[n * W + c0] += sc * h0;
    out[n * W + c1] += sc * h1;
    __syncthreads();  // red[] reuse across row iterations
  }
}

extern "C" void kernel_launch(void* const* d_in, const int* in_sizes, int n_in,
                              void* d_out, int out_size, void* d_ws, size_t ws_size,
                              hipStream_t stream) {
  const float* x     = (const float*)d_in[0];
  const float* freq  = (const float*)d_in[1];
  const float* alpha = (const float*)d_in[2];
  const float* gate  = (const float*)d_in[3];
  const float* gamma = (const float*)d_in[4];
  const float* beta  = (const float*)d_in[5];
  const float* wloc  = (const float*)d_in[6];
  const float* bloc  = (const float*)d_in[7];
  float* out = (float*)d_out;

  char* ws = (char*)d_ws;
  float* partial       = (float*)(ws + OFF_PARTIAL);
  unsigned* nnz        = (unsigned*)(ws + OFF_NNZ);
  __hip_bfloat16* xn   = (__hip_bfloat16*)(ws + OFF_XN);
  __hip_bfloat16* wb   = (__hip_bfloat16*)(ws + OFF_WB);
  unsigned* eArr       = (unsigned*)(ws + OFF_E);
  float* tArr          = (float*)(ws + OFF_T);
  float* cArr          = (float*)(ws + OFF_C);

  hipLaunchKernelGGL(ln_prep, dim3(N_TOK), dim3(256), 0, stream,
                     x, freq, gamma, beta, wloc, xn, wb, partial, nnz);
  hipLaunchKernelGGL(thr_compact, dim3(512), dim3(256), 0, stream,
                     freq, alpha, gate, partial, nnz, eArr, tArr, cArr);
  hipLaunchKernelGGL(gemm_gelu, dim3(512), dim3(64), 0, stream,
                     xn, wb, bloc, out);
  hipLaunchKernelGGL(spectral_final, dim3(512), dim3(256), 0, stream,
                     xn, nnz, eArr, tArr, cArr, out);
}

// Round 3
// 102.951 us; speedup vs baseline: 1.0043x; 1.0043x over previous
//
#include <hip/hip_runtime.h>
#include <hip/hip_bf16.h>
#include <math.h>

// Problem constants
#define N_TOK 4096
#define W 512
#define F_TOT 1024
#define FW (F_TOT * W)   // 524288

// Workspace layout (bytes) — ~10.6 MB total
#define OFF_PARTIAL 0          // 1024 floats: per-wave max|freq| partials
#define OFF_NNZ     4096       // 1 uint: nonzero thr_w count
#define OFF_XN      8192       // 4096*512 bf16 = 4 MB (x_n, MFMA A operand)
#define OFF_WB      4202496    // 512*512 bf16 = 512 KB (w_loc, MFMA B operand)
#define OFF_E       4726784    // FW uints  (2 MB) nonzero thr_w element ids
#define OFF_T       6823936    // FW floats (2 MB) thr_w values
#define OFF_C       8921088    // FW floats (2 MB) scaled freqs

typedef __attribute__((ext_vector_type(8))) short bf16x8;
typedef __attribute__((ext_vector_type(4))) short bf16x4;
typedef __attribute__((ext_vector_type(4))) float f32x4;

// Kernel 1 (1536 blocks x 256, 4 waves each, no __syncthreads anywhere):
//  - blocks 0..1023:    LayerNorm; wave w does row b*4+w via shuffle reduce
//  - blocks 1024..1279: max|freq| partials, one per wave -> partial[0..1023]
//                       (block 1024, t==0 also zeroes nnz)
//  - blocks 1280..1535: convert w_loc fp32 -> bf16 (float4 in, bf16x4 out)
__global__ __launch_bounds__(256) void ln_prep(
    const float* __restrict__ x, const float* __restrict__ freq,
    const float* __restrict__ gamma, const float* __restrict__ beta,
    const float* __restrict__ wloc, __hip_bfloat16* __restrict__ xn,
    __hip_bfloat16* __restrict__ wb, float* __restrict__ partial,
    unsigned* __restrict__ nnz) {
  const int b = blockIdx.x, t = threadIdx.x;
  const int wv = t >> 6, lane = t & 63;
  if (b < 1024) {
    const int row = b * 4 + wv;
    const float4* xr = (const float4*)(x + row * W);
    const float4 p0 = xr[lane * 2];
    const float4 p1 = xr[lane * 2 + 1];
    float s  = p0.x + p0.y + p0.z + p0.w + p1.x + p1.y + p1.z + p1.w;
    float ss = p0.x*p0.x + p0.y*p0.y + p0.z*p0.z + p0.w*p0.w
             + p1.x*p1.x + p1.y*p1.y + p1.z*p1.z + p1.w*p1.w;
#pragma unroll
    for (int m = 32; m > 0; m >>= 1) {
      s  += __shfl_xor(s, m);
      ss += __shfl_xor(ss, m);
    }
    const float mu = s * (1.0f / W);
    const float var = ss * (1.0f / W) - mu * mu;
    const float rstd = rsqrtf(var + 1e-5f);
    const float4 g0 = ((const float4*)gamma)[lane * 2];
    const float4 g1 = ((const float4*)gamma)[lane * 2 + 1];
    const float4 be0 = ((const float4*)beta)[lane * 2];
    const float4 be1 = ((const float4*)beta)[lane * 2 + 1];
    alignas(16) __hip_bfloat16 o[8];
    o[0] = __float2bfloat16((p0.x - mu) * rstd * g0.x + be0.x);
    o[1] = __float2bfloat16((p0.y - mu) * rstd * g0.y + be0.y);
    o[2] = __float2bfloat16((p0.z - mu) * rstd * g0.z + be0.z);
    o[3] = __float2bfloat16((p0.w - mu) * rstd * g0.w + be0.w);
    o[4] = __float2bfloat16((p1.x - mu) * rstd * g1.x + be1.x);
    o[5] = __float2bfloat16((p1.y - mu) * rstd * g1.y + be1.y);
    o[6] = __float2bfloat16((p1.z - mu) * rstd * g1.z + be1.z);
    o[7] = __float2bfloat16((p1.w - mu) * rstd * g1.w + be1.w);
    *(bf16x8*)(xn + row * W + lane * 8) = *(const bf16x8*)o;
  } else if (b < 1280) {
    const int b2 = b - 1024;                     // 256 blocks, 2048 elems each
    const float4* fp = (const float4*)(freq + b2 * 2048 + wv * 512);
    const float4 q0 = fp[lane * 2];
    const float4 q1 = fp[lane * 2 + 1];
    float mx = fmaxf(fmaxf(fmaxf(fabsf(q0.x), fabsf(q0.y)), fmaxf(fabsf(q0.z), fabsf(q0.w))),
                     fmaxf(fmaxf(fabsf(q1.x), fabsf(q1.y)), fmaxf(fabsf(q1.z), fabsf(q1.w))));
#pragma unroll
    for (int m = 32; m > 0; m >>= 1) mx = fmaxf(mx, __shfl_xor(mx, m));
    if (lane == 0) partial[b2 * 4 + wv] = mx;
    if (b == 1024 && t == 0) *nnz = 0u;
  } else {
    const int i4 = ((b - 1280) * 256 + t);       // 256 blocks cover 512*512
    const float4 v = ((const float4*)wloc)[i4];
    alignas(8) __hip_bfloat16 o[4];
    o[0] = __float2bfloat16(v.x);
    o[1] = __float2bfloat16(v.y);
    o[2] = __float2bfloat16(v.z);
    o[3] = __float2bfloat16(v.w);
    *(bf16x4*)(wb + i4 * 4) = *(const bf16x4*)o;
  }
}

// Kernel 2: thr_w = sign(raw)*relu(|raw|-TAU)*win, compacted to nonzero list.
// win = exp(-6*(f/max|f|)^2), f = 0.8*freq.
__global__ __launch_bounds__(256) void thr_compact(
    const float* __restrict__ freq, const float* __restrict__ alpha,
    const float* __restrict__ gate, const float* __restrict__ partial,
    unsigned* __restrict__ nnz, unsigned* __restrict__ eArr,
    float* __restrict__ tArr, float* __restrict__ cArr) {
  __shared__ float red[256];
  const int t = threadIdx.x;
  red[t] = fmaxf(fmaxf(partial[t], partial[t + 256]),
                 fmaxf(partial[t + 512], partial[t + 768]));
  __syncthreads();
  for (int s = 128; s > 0; s >>= 1) {
    if (t < s) red[t] = fmaxf(red[t], red[t + s]);
    __syncthreads();
  }
  const float denom = red[0] * 0.8f;  // max|f|
  const bool tiny = denom < 1e-8f;
  const float inv = tiny ? 0.0f : (1.0f / denom);
  const int base = blockIdx.x * 1024 + t;
#pragma unroll
  for (int j = 0; j < 4; ++j) {
    const int e = base + j * 256;
    const float f = freq[e] * 0.8f;
    const float raw = alpha[e] * gate[e];
    const float v = fabsf(raw) - 1e-3f;  // TAU
    if (v > 0.0f) {
      const float r = f * inv;
      const float win = tiny ? 1.0f : expf(-6.0f * r * r);
      const float tw = copysignf(v, raw) * win;
      const unsigned idx = atomicAdd(nnz, 1u);
      eArr[idx] = (unsigned)e;
      tArr[idx] = tw;
      cArr[idx] = f;
    }
  }
}

// Kernel 3: h_local = GELU(xn @ wloc^T + b) via MFMA 16x16x32 bf16.
// Wave-tile 16x64 (acc = 4 frags), 2048 single-wave blocks -> 8 waves/CU.
// Software-pipelined: next k-step fragments load during current MFMAs.
// A-frag: A[m=lane&15][k=q*8+j]; B-frag: B[k][n=lane&15] from wb=[N][K].
// C/D: col=lane&15, row=q*4+reg  [measured m89/m91]
__global__ __launch_bounds__(64) void gemm_gelu(
    const __hip_bfloat16* __restrict__ xn, const __hip_bfloat16* __restrict__ wb,
    const float* __restrict__ bias, float* __restrict__ out) {
  const int tm = blockIdx.x >> 3;   // 256 row tiles of 16
  const int tn = blockIdx.x & 7;    // 8 col tiles of 64
  const int lane = threadIdx.x;
  const int m = lane & 15;
  const int q = lane >> 4;
  const short* A = (const short*)xn + (tm * 16 + m) * W + q * 8;
  const short* B = (const short*)wb + (tn * 64 + m) * W + q * 8;
  f32x4 acc[4] = {};

  bf16x8 a_cur = *(const bf16x8*)A;
  bf16x8 b_cur[4];
#pragma unroll
  for (int j = 0; j < 4; ++j) b_cur[j] = *(const bf16x8*)(B + (j * 16) * W);

#pragma unroll
  for (int k0 = 0; k0 < W; k0 += 32) {
    bf16x8 a_nxt;
    bf16x8 b_nxt[4];
    if (k0 + 32 < W) {
      a_nxt = *(const bf16x8*)(A + k0 + 32);
#pragma unroll
      for (int j = 0; j < 4; ++j)
        b_nxt[j] = *(const bf16x8*)(B + (j * 16) * W + k0 + 32);
    }
#pragma unroll
    for (int j = 0; j < 4; ++j)
      acc[j] = __builtin_amdgcn_mfma_f32_16x16x32_bf16(a_cur, b_cur[j], acc[j], 0, 0, 0);
    a_cur = a_nxt;
#pragma unroll
    for (int j = 0; j < 4; ++j) b_cur[j] = b_nxt[j];
  }

#pragma unroll
  for (int j = 0; j < 4; ++j) {
    const int col = tn * 64 + j * 16 + m;
    const float bv = bias[col];
#pragma unroll
    for (int r = 0; r < 4; ++r) {
      const int row = tm * 16 + q * 4 + r;
      const float v = acc[j][r] + bv;
      const float g = 0.5f * v * (1.0f + erff(v * 0.70710678118654752f));
      out[row * W + col] = g;
    }
  }
}

// Kernel 4: spectral accumulation + RMS norm + residual add (gather-style).
// For the actual inputs nnz==0 -> immediate exit (out already = h_local).
__global__ __launch_bounds__(256) void spectral_final(
    const __hip_bfloat16* __restrict__ xn, const unsigned* __restrict__ nnz,
    const unsigned* __restrict__ eArr, const float* __restrict__ tArr,
    const float* __restrict__ cArr, float* __restrict__ out) {
  const unsigned cnt = *nnz;
  if (cnt == 0) return;
  __shared__ float red[256];
  const int t = threadIdx.x;
  for (int n = blockIdx.x; n < N_TOK; n += gridDim.x) {
    const int c0 = t, c1 = t + 256;
    const float x0 = __bfloat162float(xn[n * W + c0]);
    const float x1 = __bfloat162float(xn[n * W + c1]);
    float h0 = 0.0f, h1 = 0.0f;
    for (unsigned i = 0; i < cnt; ++i) {
      const unsigned e = eArr[i];
      const int we = (int)(e & (W - 1));
      const float tw = tArr[i];
      const float cf = cArr[i];
      if (we == c0) h0 += tw * sinf(x0 * cf);
      else if (we == c1) h1 += tw * sinf(x1 * cf);
    }
    red[t] = h0 * h0 + h1 * h1;
    __syncthreads();
    for (int s = 128; s > 0; s >>= 1) {
      if (t < s) red[t] += red[t + s];
      __syncthreads();
    }
    const float rms = sqrtf(red[0] * (1.0f / W) + 1e-8f);
    const float sc = 0.25f / rms;
    out[n * W + c0] += sc * h0;
    out[n * W + c1] += sc * h1;
    __syncthreads();  // red[] reuse across row iterations
  }
}

extern "C" void kernel_launch(void* const* d_in, const int* in_sizes, int n_in,
                              void* d_out, int out_size, void* d_ws, size_t ws_size,
                              hipStream_t stream) {
  const float* x     = (const float*)d_in[0];
  const float* freq  = (const float*)d_in[1];
  const float* alpha = (const float*)d_in[2];
  const float* gate  = (const float*)d_in[3];
  const float* gamma = (const float*)d_in[4];
  const float* beta  = (const float*)d_in[5];
  const float* wloc  = (const float*)d_in[6];
  const float* bloc  = (const float*)d_in[7];
  float* out = (float*)d_out;

  char* ws = (char*)d_ws;
  float* partial       = (float*)(ws + OFF_PARTIAL);
  unsigned* nnz        = (unsigned*)(ws + OFF_NNZ);
  __hip_bfloat16* xn   = (__hip_bfloat16*)(ws + OFF_XN);
  __hip_bfloat16* wb   = (__hip_bfloat16*)(ws + OFF_WB);
  unsigned* eArr       = (unsigned*)(ws + OFF_E);
  float* tArr          = (float*)(ws + OFF_T);
  float* cArr          = (float*)(ws + OFF_C);

  hipLaunchKernelGGL(ln_prep, dim3(1536), dim3(256), 0, stream,
                     x, freq, gamma, beta, wloc, xn, wb, partial, nnz);
  hipLaunchKernelGGL(thr_compact, dim3(512), dim3(256), 0, stream,
                     freq, alpha, gate, partial, nnz, eArr, tArr, cArr);
  hipLaunchKernelGGL(gemm_gelu, dim3(2048), dim3(64), 0, stream,
                     xn, wb, bloc, out);
  hipLaunchKernelGGL(spectral_final, dim3(512), dim3(256), 0, stream,
                     xn, nnz, eArr, tArr, cArr, out);
}

// Round 4
// 100.291 us; speedup vs baseline: 1.0309x; 1.0265x over previous
//
#include <hip/hip_runtime.h>
#include <hip/hip_bf16.h>
#include <math.h>

// Problem constants
#define N_TOK 4096
#define W 512
#define F_TOT 1024
#define FW (F_TOT * W)   // 524288

// Workspace layout (bytes) — ~10.6 MB used (ws is 256 MiB; its re-poison by
// the harness costs ~45 us/iter and dominates dur_us — see R3 post-mortem)
#define OFF_PARTIAL 0          // 1024 floats: per-wave max|freq| partials
#define OFF_NNZ     4096       // 1 uint: nonzero thr_w count
#define OFF_XN      8192       // 4096*512 bf16 = 4 MB (x_n, MFMA A operand)
#define OFF_WB      4202496    // 512*512 bf16 = 512 KB (w_loc, MFMA B operand)
#define OFF_E       4726784    // FW uints  (2 MB) nonzero thr_w element ids
#define OFF_T       6823936    // FW floats (2 MB) thr_w values
#define OFF_C       8921088    // FW floats (2 MB) scaled freqs

typedef __attribute__((ext_vector_type(8))) short bf16x8;
typedef __attribute__((ext_vector_type(4))) short bf16x4;
typedef __attribute__((ext_vector_type(4))) float f32x4;

// Kernel 1 (1536 blocks x 256, 4 waves each, no __syncthreads anywhere):
//  - blocks 0..1023:    LayerNorm; wave w does row b*4+w via shuffle reduce
//  - blocks 1024..1279: max|freq| partials, one per wave -> partial[0..1023]
//                       (block 1024, t==0 also zeroes nnz)
//  - blocks 1280..1535: convert w_loc fp32 -> bf16 (float4 in, bf16x4 out)
__global__ __launch_bounds__(256) void ln_prep(
    const float* __restrict__ x, const float* __restrict__ freq,
    const float* __restrict__ gamma, const float* __restrict__ beta,
    const float* __restrict__ wloc, __hip_bfloat16* __restrict__ xn,
    __hip_bfloat16* __restrict__ wb, float* __restrict__ partial,
    unsigned* __restrict__ nnz) {
  const int b = blockIdx.x, t = threadIdx.x;
  const int wv = t >> 6, lane = t & 63;
  if (b < 1024) {
    const int row = b * 4 + wv;
    const float4* xr = (const float4*)(x + row * W);
    const float4 p0 = xr[lane * 2];
    const float4 p1 = xr[lane * 2 + 1];
    float s  = p0.x + p0.y + p0.z + p0.w + p1.x + p1.y + p1.z + p1.w;
    float ss = p0.x*p0.x + p0.y*p0.y + p0.z*p0.z + p0.w*p0.w
             + p1.x*p1.x + p1.y*p1.y + p1.z*p1.z + p1.w*p1.w;
#pragma unroll
    for (int m = 32; m > 0; m >>= 1) {
      s  += __shfl_xor(s, m);
      ss += __shfl_xor(ss, m);
    }
    const float mu = s * (1.0f / W);
    const float var = ss * (1.0f / W) - mu * mu;
    const float rstd = rsqrtf(var + 1e-5f);
    const float4 g0 = ((const float4*)gamma)[lane * 2];
    const float4 g1 = ((const float4*)gamma)[lane * 2 + 1];
    const float4 be0 = ((const float4*)beta)[lane * 2];
    const float4 be1 = ((const float4*)beta)[lane * 2 + 1];
    alignas(16) __hip_bfloat16 o[8];
    o[0] = __float2bfloat16((p0.x - mu) * rstd * g0.x + be0.x);
    o[1] = __float2bfloat16((p0.y - mu) * rstd * g0.y + be0.y);
    o[2] = __float2bfloat16((p0.z - mu) * rstd * g0.z + be0.z);
    o[3] = __float2bfloat16((p0.w - mu) * rstd * g0.w + be0.w);
    o[4] = __float2bfloat16((p1.x - mu) * rstd * g1.x + be1.x);
    o[5] = __float2bfloat16((p1.y - mu) * rstd * g1.y + be1.y);
    o[6] = __float2bfloat16((p1.z - mu) * rstd * g1.z + be1.z);
    o[7] = __float2bfloat16((p1.w - mu) * rstd * g1.w + be1.w);
    *(bf16x8*)(xn + row * W + lane * 8) = *(const bf16x8*)o;
  } else if (b < 1280) {
    const int b2 = b - 1024;                     // 256 blocks, 2048 elems each
    const float4* fp = (const float4*)(freq + b2 * 2048 + wv * 512);
    const float4 q0 = fp[lane * 2];
    const float4 q1 = fp[lane * 2 + 1];
    float mx = fmaxf(fmaxf(fmaxf(fabsf(q0.x), fabsf(q0.y)), fmaxf(fabsf(q0.z), fabsf(q0.w))),
                     fmaxf(fmaxf(fabsf(q1.x), fabsf(q1.y)), fmaxf(fabsf(q1.z), fabsf(q1.w))));
#pragma unroll
    for (int m = 32; m > 0; m >>= 1) mx = fmaxf(mx, __shfl_xor(mx, m));
    if (lane == 0) partial[b2 * 4 + wv] = mx;
    if (b == 1024 && t == 0) *nnz = 0u;
  } else {
    const int i4 = ((b - 1280) * 256 + t);       // 256 blocks cover 512*512
    const float4 v = ((const float4*)wloc)[i4];
    alignas(8) __hip_bfloat16 o[4];
    o[0] = __float2bfloat16(v.x);
    o[1] = __float2bfloat16(v.y);
    o[2] = __float2bfloat16(v.z);
    o[3] = __float2bfloat16(v.w);
    *(bf16x4*)(wb + i4 * 4) = *(const bf16x4*)o;
  }
}

// Kernel 2 (2560 x 64): fused thr_compact + GEMM-GELU. Both halves depend
// only on kernel 1, so the compaction's memory work overlaps the GEMM.
//  - blocks 0..511: thr_w = sign(raw)*relu(|raw|-TAU)*win, compacted to a
//    nonzero list. win = exp(-6*(f/max|f|)^2), f = 0.8*freq. Pure shuffle
//    reduce of the 1024 max-partials, no LDS/barriers.
//  - blocks 512..2559: h_local = GELU(xn @ wloc^T + b), MFMA 16x16x32 bf16.
//    Wave-tile 16x64 (acc = 4 frags), 2048 single-wave tiles -> 8 waves/CU.
//    Software-pipelined next-k fragment prefetch.
//    A-frag: A[m=lane&15][k=q*8+j]; B-frag: B[k][n=lane&15] (wb = [N][K]).
//    C/D: col=lane&15, row=q*4+reg  [measured m89/m91]
__global__ __launch_bounds__(64) void gemm_thr(
    const __hip_bfloat16* __restrict__ xn, const __hip_bfloat16* __restrict__ wb,
    const float* __restrict__ bias, float* __restrict__ out,
    const float* __restrict__ freq, const float* __restrict__ alpha,
    const float* __restrict__ gate, const float* __restrict__ partial,
    unsigned* __restrict__ nnz, unsigned* __restrict__ eArr,
    float* __restrict__ tArr, float* __restrict__ cArr) {
  const int bid = blockIdx.x;
  const int lane = threadIdx.x;

  if (bid < 512) {  // ---- thr_compact path ----
    float mx = 0.0f;
#pragma unroll
    for (int j = 0; j < 16; ++j) mx = fmaxf(mx, partial[lane + j * 64]);
#pragma unroll
    for (int m = 32; m > 0; m >>= 1) mx = fmaxf(mx, __shfl_xor(mx, m));
    const float denom = mx * 0.8f;  // max|f|
    const bool tiny = denom < 1e-8f;
    const float inv = tiny ? 0.0f : (1.0f / denom);
    const int base = bid * 1024 + lane;
#pragma unroll
    for (int j = 0; j < 16; ++j) {
      const int e = base + j * 64;
      const float f = freq[e] * 0.8f;
      const float raw = alpha[e] * gate[e];
      const float v = fabsf(raw) - 1e-3f;  // TAU
      if (v > 0.0f) {
        const float r = f * inv;
        const float win = tiny ? 1.0f : expf(-6.0f * r * r);
        const float tw = copysignf(v, raw) * win;
        const unsigned idx = atomicAdd(nnz, 1u);
        eArr[idx] = (unsigned)e;
        tArr[idx] = tw;
        cArr[idx] = f;
      }
    }
    return;
  }

  // ---- GEMM path ----
  const int bid2 = bid - 512;
  const int tm = bid2 >> 3;   // 256 row tiles of 16
  const int tn = bid2 & 7;    // 8 col tiles of 64
  const int m = lane & 15;
  const int q = lane >> 4;
  const short* A = (const short*)xn + (tm * 16 + m) * W + q * 8;
  const short* B = (const short*)wb + (tn * 64 + m) * W + q * 8;
  f32x4 acc[4] = {};

  bf16x8 a_cur = *(const bf16x8*)A;
  bf16x8 b_cur[4];
#pragma unroll
  for (int j = 0; j < 4; ++j) b_cur[j] = *(const bf16x8*)(B + (j * 16) * W);

#pragma unroll
  for (int k0 = 0; k0 < W; k0 += 32) {
    bf16x8 a_nxt;
    bf16x8 b_nxt[4];
    if (k0 + 32 < W) {
      a_nxt = *(const bf16x8*)(A + k0 + 32);
#pragma unroll
      for (int j = 0; j < 4; ++j)
        b_nxt[j] = *(const bf16x8*)(B + (j * 16) * W + k0 + 32);
    }
#pragma unroll
    for (int j = 0; j < 4; ++j)
      acc[j] = __builtin_amdgcn_mfma_f32_16x16x32_bf16(a_cur, b_cur[j], acc[j], 0, 0, 0);
    a_cur = a_nxt;
#pragma unroll
    for (int j = 0; j < 4; ++j) b_cur[j] = b_nxt[j];
  }

#pragma unroll
  for (int j = 0; j < 4; ++j) {
    const int col = tn * 64 + j * 16 + m;
    const float bv = bias[col];
#pragma unroll
    for (int r = 0; r < 4; ++r) {
      const int row = tm * 16 + q * 4 + r;
      const float v = acc[j][r] + bv;
      const float g = 0.5f * v * (1.0f + erff(v * 0.70710678118654752f));
      out[row * W + col] = g;
    }
  }
}

// Kernel 3: spectral accumulation + RMS norm + residual add (gather-style),
// 64-thread barrier-free form (8 cols/lane, shuffle RMS reduce).
// For the actual inputs nnz==0 -> immediate exit (out already = h_local).
__global__ __launch_bounds__(64) void spectral_final(
    const __hip_bfloat16* __restrict__ xn, const unsigned* __restrict__ nnz,
    const unsigned* __restrict__ eArr, const float* __restrict__ tArr,
    const float* __restrict__ cArr, float* __restrict__ out) {
  const unsigned cnt = *nnz;
  if (cnt == 0) return;
  const int lane = threadIdx.x;
  for (int n = blockIdx.x; n < N_TOK; n += gridDim.x) {
    float xv[8], h[8];
#pragma unroll
    for (int j = 0; j < 8; ++j) {
      xv[j] = __bfloat162float(xn[n * W + lane + j * 64]);
      h[j] = 0.0f;
    }
    for (unsigned i = 0; i < cnt; ++i) {
      const unsigned e = eArr[i];
      const int we = (int)(e & (W - 1));
      if ((we & 63) == lane) {
        const int j = we >> 6;
        h[j] += tArr[i] * sinf(xv[j] * cArr[i]);
      }
    }
    float ss = 0.0f;
#pragma unroll
    for (int j = 0; j < 8; ++j) ss += h[j] * h[j];
#pragma unroll
    for (int m = 32; m > 0; m >>= 1) ss += __shfl_xor(ss, m);
    const float rms = sqrtf(ss * (1.0f / W) + 1e-8f);
    const float sc = 0.25f / rms;
#pragma unroll
    for (int j = 0; j < 8; ++j) out[n * W + lane + j * 64] += sc * h[j];
  }
}

extern "C" void kernel_launch(void* const* d_in, const int* in_sizes, int n_in,
                              void* d_out, int out_size, void* d_ws, size_t ws_size,
                              hipStream_t stream) {
  const float* x     = (const float*)d_in[0];
  const float* freq  = (const float*)d_in[1];
  const float* alpha = (const float*)d_in[2];
  const float* gate  = (const float*)d_in[3];
  const float* gamma = (const float*)d_in[4];
  const float* beta  = (const float*)d_in[5];
  const float* wloc  = (const float*)d_in[6];
  const float* bloc  = (const float*)d_in[7];
  float* out = (float*)d_out;

  char* ws = (char*)d_ws;
  float* partial       = (float*)(ws + OFF_PARTIAL);
  unsigned* nnz        = (unsigned*)(ws + OFF_NNZ);
  __hip_bfloat16* xn   = (__hip_bfloat16*)(ws + OFF_XN);
  __hip_bfloat16* wb   = (__hip_bfloat16*)(ws + OFF_WB);
  unsigned* eArr       = (unsigned*)(ws + OFF_E);
  float* tArr          = (float*)(ws + OFF_T);
  float* cArr          = (float*)(ws + OFF_C);

  hipLaunchKernelGGL(ln_prep, dim3(1536), dim3(256), 0, stream,
                     x, freq, gamma, beta, wloc, xn, wb, partial, nnz);
  hipLaunchKernelGGL(gemm_thr, dim3(2560), dim3(64), 0, stream,
                     xn, wb, bloc, out, freq, alpha, gate, partial,
                     nnz, eArr, tArr, cArr);
  hipLaunchKernelGGL(spectral_final, dim3(512), dim3(64), 0, stream,
                     xn, nnz, eArr, tArr, cArr, out);
}